// Round 8
// baseline (179.533 us; speedup 1.0000x reference)
//
#include <hip/hip_runtime.h>

#define DIM   1024
#define NQKV  3072
#define SEQ   2048
#define HEADS 16
#define DHEAD 64
#define M_TOT 4096   // batch(2) * seq(2048)

typedef __bf16 bf16;
typedef __bf16 bf16x8 __attribute__((ext_vector_type(8)));
typedef float  f32x4  __attribute__((ext_vector_type(4)));

typedef const __attribute__((address_space(1))) unsigned int gu32;
typedef __attribute__((address_space(3))) unsigned int su32;

static __device__ __forceinline__ unsigned short f2b(float f) {
    bf16 h = (bf16)f;
    return __builtin_bit_cast(unsigned short, h);
}

// ---------------- kernel 1: fused prep (cast x -> bf16 | transpose+scale W) ----------------
#define CAST_BLOCKS (M_TOT * DIM / (256 * 4))
__global__ void prep_kernel(const float* __restrict__ x,
                            unsigned short* __restrict__ xb,
                            const float* __restrict__ W,
                            unsigned short* __restrict__ Wt) {
    __shared__ float tile[32][33];
    const int id  = blockIdx.x;
    const int tid = threadIdx.x;
    if (id < CAST_BLOCKS) {
        int i = (id * 256 + tid) * 4;
        float4 v = *(const float4*)(x + i);
        ushort4 o;
        o.x = f2b(v.x); o.y = f2b(v.y); o.z = f2b(v.z); o.w = f2b(v.w);
        *(ushort4*)(xb + i) = o;
    } else {
        int t  = id - CAST_BLOCKS;
        int nb = t % (NQKV / 32);
        int kb = t / (NQKV / 32);
        int tx = tid & 31, ty0 = tid >> 5;
        for (int ty = ty0; ty < 32; ty += 8)
            tile[ty][tx] = W[(size_t)(kb*32 + ty)*NQKV + nb*32 + tx];
        __syncthreads();
        for (int ty = ty0; ty < 32; ty += 8) {
            int n = nb*32 + ty;
            float s = (n < 1024) ? 0.18033688f : 1.0f;   // 0.125 * log2(e)
            Wt[(size_t)n*DIM + kb*32 + tx] = f2b(tile[tx][ty] * s);
        }
    }
}

// ---------------- kernel 2: QKV GEMM, LDS-restaged coalesced epilogue ----------------
#define LDC 136
__global__ __launch_bounds__(256) void qkv_gemm_kernel(
    const unsigned short* __restrict__ A,
    const unsigned short* __restrict__ Bt,
    unsigned short* __restrict__ Qw,
    unsigned short* __restrict__ Kw,
    unsigned short* __restrict__ Vtw)
{
    __shared__ __align__(16) unsigned char smem[128 * LDC * 2];   // 34816 B
    unsigned short* As = (unsigned short*)smem;
    unsigned short* Bs = (unsigned short*)(smem + 16384);
    unsigned short* Cs = (unsigned short*)smem;

    const int tid  = threadIdx.x;
    const int m0   = blockIdx.y * 128;
    const int n0   = blockIdx.x * 128;
    const int w    = tid >> 6;
    const int lane = tid & 63;
    const int l16  = lane & 15;
    const int quad = lane >> 4;
    const int wm   = (w >> 1) * 64;
    const int wn   = (w & 1) * 64;
    const int srow = lane >> 3;
    const int scol = (lane & 7) * 8;

    f32x4 acc[4][4];
    const f32x4 fzero = {0.f, 0.f, 0.f, 0.f};
    for (int i = 0; i < 4; i++)
        for (int j = 0; j < 4; j++) acc[i][j] = fzero;

    const unsigned short* Ag = A  + (size_t)(m0 + w * 32 + srow) * DIM + scol;
    const unsigned short* Bg = Bt + (size_t)(n0 + w * 32 + srow) * DIM + scol;

    for (int kt = 0; kt < DIM; kt += 64) {
        #pragma unroll
        for (int j = 0; j < 4; j++) {
            __builtin_amdgcn_global_load_lds((gu32*)(Ag + kt + (size_t)j * 8 * DIM),
                                             (su32*)&As[(w * 32 + j * 8) * 64], 16, 0, 0);
            __builtin_amdgcn_global_load_lds((gu32*)(Bg + kt + (size_t)j * 8 * DIM),
                                             (su32*)&Bs[(w * 32 + j * 8) * 64], 16, 0, 0);
        }
        __syncthreads();
        #pragma unroll
        for (int s = 0; s < 2; s++) {
            bf16x8 af[4], bfr[4];
            #pragma unroll
            for (int i = 0; i < 4; i++) {
                af[i]  = *(const bf16x8*)(&As[(wm + i * 16 + l16) * 64 + s * 32 + quad * 8]);
                bfr[i] = *(const bf16x8*)(&Bs[(wn + i * 16 + l16) * 64 + s * 32 + quad * 8]);
            }
            #pragma unroll
            for (int i = 0; i < 4; i++)
                #pragma unroll
                for (int j = 0; j < 4; j++)
                    acc[i][j] = __builtin_amdgcn_mfma_f32_16x16x32_bf16(af[i], bfr[j], acc[i][j], 0, 0, 0);
        }
        __syncthreads();
    }

    const int part = n0 >> 10;
    const int h0   = (n0 & 1023) >> 6;
    const int b    = m0 >> 11;
    const int np0  = m0 & 2047;

    if (part < 2) {
        #pragma unroll
        for (int i = 0; i < 4; i++)
            #pragma unroll
            for (int j = 0; j < 4; j++)
                #pragma unroll
                for (int r = 0; r < 4; r++)
                    Cs[(wm + i * 16 + quad * 4 + r) * LDC + wn + j * 16 + l16] = f2b(acc[i][j][r]);
        __syncthreads();
        unsigned short* dst = (part == 0) ? Qw : Kw;
        #pragma unroll
        for (int pass = 0; pass < 8; pass++) {
            int mi = pass * 16 + (tid >> 4);
            int ci = (tid & 15) * 8;
            uint4 v = *(const uint4*)&Cs[mi * LDC + ci];
            int bh = b * HEADS + h0 + (ci >> 6);
            *(uint4*)&dst[((size_t)bh * SEQ + np0 + mi) * DHEAD + (ci & 63)] = v;
        }
    } else {
        #pragma unroll
        for (int i = 0; i < 4; i++)
            #pragma unroll
            for (int j = 0; j < 4; j++) {
                ushort4 pk;
                pk.x = f2b(acc[i][j][0]); pk.y = f2b(acc[i][j][1]);
                pk.z = f2b(acc[i][j][2]); pk.w = f2b(acc[i][j][3]);
                *(ushort4*)&Cs[(wn + j * 16 + l16) * LDC + wm + i * 16 + quad * 4] = pk;
            }
        __syncthreads();
        #pragma unroll
        for (int pass = 0; pass < 8; pass++) {
            int ci = pass * 16 + (tid >> 4);
            int mi = (tid & 15) * 8;
            uint4 v = *(const uint4*)&Cs[ci * LDC + mi];
            int bh = b * HEADS + h0 + (ci >> 6);
            *(uint4*)&Vtw[((size_t)bh * DHEAD + (ci & 63)) * SEQ + np0 + mi] = v;
        }
    }
}

// ---------------- kernel 3: flash attention + residual ----------------
// 64-key tiles, double-buffered LDS (ONE barrier per tile), swizzled Ks:
// chunk c of row r stored at chunk position (c + 2*(r>>3)) & 7 -> the QK
// read pattern (rows differing by 8*(l16>>2), which is bank-invariant at
// stride-72) becomes exactly 2-way per bank = free. Vs unswizzled (already
// 2-way). Key-permuted S^T keeps P in-register; denominator via ones-MFMA.
#define LDK 72
__global__ __launch_bounds__(256) void attn_kernel(
    const unsigned short* __restrict__ Qw,
    const unsigned short* __restrict__ Kw,
    const unsigned short* __restrict__ Vtw,
    const float* __restrict__ x,
    float* __restrict__ out)
{
    __shared__ __align__(16) unsigned short Ks[2][64 * LDK];  // [key][d], swizzled chunks
    __shared__ __align__(16) unsigned short Vs[2][64 * LDK];  // V^T: [d][key]
    const int id  = blockIdx.x;
    const int qt  = id >> 5;
    const int bh  = ((id & 7) << 2) | ((id >> 3) & 3);        // 4 bh per XCD
    const int tid = threadIdx.x;
    const int w   = tid >> 6, lane = tid & 63;
    const int l16 = lane & 15, quad = lane >> 4;

    const unsigned short* Qbase = Qw + ((size_t)bh * SEQ + qt * 64 + w * 16 + l16) * DHEAD;
    bf16x8 qf[2];
    qf[0] = *(const bf16x8*)(Qbase + quad * 8);
    qf[1] = *(const bf16x8*)(Qbase + 32 + quad * 8);

    const int prow = ((l16 >> 2) << 3) | (l16 & 3);
    // swizzled QK read chunk offsets (independent of ki: 2*(sigma>>3) == 2*(l16>>2) mod 8)
    const int co0 = (((quad + 2 * (l16 >> 2)) & 7)) * 8;
    const int co1 = (((4 + quad + 2 * (l16 >> 2)) & 7)) * 8;

    bf16x8 ones;
    #pragma unroll
    for (int j = 0; j < 8; j++) ones[j] = (bf16)1.0f;

    f32x4 o[4], dsum;
    const f32x4 fzero = {0.f, 0.f, 0.f, 0.f};
    #pragma unroll
    for (int d = 0; d < 4; d++) o[d] = fzero;
    dsum = fzero;

    const unsigned short* Kg = Kw  + (size_t)bh * SEQ * DHEAD;
    const unsigned short* Vg = Vtw + (size_t)bh * DHEAD * SEQ;

    const int r0 = tid >> 3, c0 = (tid & 7) * 8;
    // swizzled K write chunk (same for rows r0 and r0+32: +32 rows -> +8 to 2*(r>>3), mod 8 invariant)
    const int kwc = (((tid & 7) + 2 * (r0 >> 3)) & 7) * 8;

    // prologue: stage tile 0, preload tile 1
    uint4 kreg0 = *(const uint4*)(Kg + (size_t)r0 * DHEAD + c0);
    uint4 kreg1 = *(const uint4*)(Kg + (size_t)(r0 + 32) * DHEAD + c0);
    uint4 vreg0 = *(const uint4*)(Vg + (size_t)r0 * SEQ + c0);
    uint4 vreg1 = *(const uint4*)(Vg + (size_t)(r0 + 32) * SEQ + c0);
    *(uint4*)&Ks[0][r0 * LDK + kwc]        = kreg0;
    *(uint4*)&Ks[0][(r0 + 32) * LDK + kwc] = kreg1;
    *(uint4*)&Vs[0][r0 * LDK + c0]         = vreg0;
    *(uint4*)&Vs[0][(r0 + 32) * LDK + c0]  = vreg1;
    kreg0 = *(const uint4*)(Kg + (size_t)(64 + r0) * DHEAD + c0);
    kreg1 = *(const uint4*)(Kg + (size_t)(64 + r0 + 32) * DHEAD + c0);
    vreg0 = *(const uint4*)(Vg + (size_t)r0 * SEQ + 64 + c0);
    vreg1 = *(const uint4*)(Vg + (size_t)(r0 + 32) * SEQ + 64 + c0);
    __syncthreads();

    for (int t = 0; t < SEQ / 64; t++) {
        const int cur = t & 1, nxt = cur ^ 1;
        // stage tile t+1 into the other buffer (regs loaded last iter)
        *(uint4*)&Ks[nxt][r0 * LDK + kwc]        = kreg0;
        *(uint4*)&Ks[nxt][(r0 + 32) * LDK + kwc] = kreg1;
        *(uint4*)&Vs[nxt][r0 * LDK + c0]         = vreg0;
        *(uint4*)&Vs[nxt][(r0 + 32) * LDK + c0]  = vreg1;
        // prefetch tile t+2 (wrap; tail loads harmless, L2-hot)
        int kvn = ((t + 2) & (SEQ / 64 - 1)) * 64;
        kreg0 = *(const uint4*)(Kg + (size_t)(kvn + r0) * DHEAD + c0);
        kreg1 = *(const uint4*)(Kg + (size_t)(kvn + r0 + 32) * DHEAD + c0);
        vreg0 = *(const uint4*)(Vg + (size_t)r0 * SEQ + kvn + c0);
        vreg1 = *(const uint4*)(Vg + (size_t)(r0 + 32) * SEQ + kvn + c0);

        // S^T = K_perm · Q^T on buffer `cur`
        f32x4 sacc[4];
        #pragma unroll
        for (int ki = 0; ki < 4; ki++) sacc[ki] = fzero;
        #pragma unroll
        for (int ki = 0; ki < 4; ki++) {
            int row = (ki >> 1) * 32 + prow + (ki & 1) * 4;
            bf16x8 kf0 = *(const bf16x8*)(&Ks[cur][row * LDK + co0]);
            sacc[ki] = __builtin_amdgcn_mfma_f32_16x16x32_bf16(kf0, qf[0], sacc[ki], 0, 0, 0);
            bf16x8 kf1 = *(const bf16x8*)(&Ks[cur][row * LDK + co1]);
            sacc[ki] = __builtin_amdgcn_mfma_f32_16x16x32_bf16(kf1, qf[1], sacc[ki], 0, 0, 0);
        }

        // p = exp2(s); C-regs are the PV A-frags; denominator via ones-MFMA
        bf16x8 pf[2];
        #pragma unroll
        for (int s = 0; s < 2; s++)
            #pragma unroll
            for (int half = 0; half < 2; half++) {
                int ki = 2 * s + half;
                #pragma unroll
                for (int r = 0; r < 4; r++)
                    pf[s][half * 4 + r] = (bf16)__builtin_amdgcn_exp2f(sacc[ki][r]);
            }

        #pragma unroll
        for (int s = 0; s < 2; s++) {
            dsum = __builtin_amdgcn_mfma_f32_16x16x32_bf16(pf[s], ones, dsum, 0, 0, 0);
            #pragma unroll
            for (int d = 0; d < 4; d++) {
                bf16x8 vf = *(const bf16x8*)(&Vs[cur][(d * 16 + l16) * LDK + s * 32 + quad * 8]);
                o[d] = __builtin_amdgcn_mfma_f32_16x16x32_bf16(pf[s], vf, o[d], 0, 0, 0);
            }
        }
        __syncthreads();
    }

    // dsum[r] = denominator of query quad*4+r (replicated across l16 lanes)
    float lr[4];
    #pragma unroll
    for (int r = 0; r < 4; r++) lr[r] = __builtin_amdgcn_rcpf(dsum[r]);

    const int b = bh >> 4, h = bh & 15;
    #pragma unroll
    for (int di = 0; di < 4; di++)
        #pragma unroll
        for (int r = 0; r < 4; r++) {
            int np  = qt * 64 + w * 16 + quad * 4 + r;
            int col = h * 64 + di * 16 + l16;
            size_t g = ((size_t)(b * SEQ + np)) * DIM + col;
            out[g] = o[di][r] * lr[r] + x[g];
        }
}

extern "C" void kernel_launch(void* const* d_in, const int* in_sizes, int n_in,
                              void* d_out, int out_size, void* d_ws, size_t ws_size,
                              hipStream_t stream) {
    const float* x  = (const float*)d_in[0];   // [2,2048,1024]
    const float* Wq = (const float*)d_in[1];   // [1024,3072]
    float* out = (float*)d_out;

    unsigned short* xb = (unsigned short*)d_ws;                  // [4096][1024]
    unsigned short* Wt = xb + (size_t)M_TOT * DIM;               // [3072][1024]
    unsigned short* Qw = Wt + (size_t)NQKV * DIM;                // [32][2048][64]
    unsigned short* Kw = Qw + (size_t)32 * SEQ * DHEAD;          // [32][2048][64]
    unsigned short* Vt = Kw + (size_t)32 * SEQ * DHEAD;          // [32][64][2048]

    prep_kernel<<<CAST_BLOCKS + (NQKV / 32) * (DIM / 32), 256, 0, stream>>>(x, xb, Wq, Wt);
    qkv_gemm_kernel<<<dim3(NQKV / 128, M_TOT / 128), 256, 0, stream>>>(xb, Wt, Qw, Kw, Vt);
    attn_kernel<<<(SEQ / 64) * 32, 256, 0, stream>>>(Qw, Kw, Vt, x, out);
}

// Round 9
// 177.761 us; speedup vs baseline: 1.0100x; 1.0100x over previous
//
#include <hip/hip_runtime.h>

#define DIM   1024
#define NQKV  3072
#define SEQ   2048
#define HEADS 16
#define DHEAD 64
#define M_TOT 4096   // batch(2) * seq(2048)

typedef __bf16 bf16;
typedef __bf16 bf16x8 __attribute__((ext_vector_type(8)));
typedef float  f32x4  __attribute__((ext_vector_type(4)));

typedef const __attribute__((address_space(1))) unsigned int gu32;
typedef __attribute__((address_space(3))) unsigned int su32;

static __device__ __forceinline__ unsigned short f2b(float f) {
    bf16 h = (bf16)f;
    return __builtin_bit_cast(unsigned short, h);
}

// ---------------- kernel 1: fused prep (cast x -> bf16 | transpose+scale W) ----------------
#define CAST_BLOCKS (M_TOT * DIM / (256 * 4))
__global__ void prep_kernel(const float* __restrict__ x,
                            unsigned short* __restrict__ xb,
                            const float* __restrict__ W,
                            unsigned short* __restrict__ Wt) {
    __shared__ float tile[32][33];
    const int id  = blockIdx.x;
    const int tid = threadIdx.x;
    if (id < CAST_BLOCKS) {
        int i = (id * 256 + tid) * 4;
        float4 v = *(const float4*)(x + i);
        ushort4 o;
        o.x = f2b(v.x); o.y = f2b(v.y); o.z = f2b(v.z); o.w = f2b(v.w);
        *(ushort4*)(xb + i) = o;
    } else {
        int t  = id - CAST_BLOCKS;
        int nb = t % (NQKV / 32);
        int kb = t / (NQKV / 32);
        int tx = tid & 31, ty0 = tid >> 5;
        for (int ty = ty0; ty < 32; ty += 8)
            tile[ty][tx] = W[(size_t)(kb*32 + ty)*NQKV + nb*32 + tx];
        __syncthreads();
        for (int ty = ty0; ty < 32; ty += 8) {
            int n = nb*32 + ty;
            float s = (n < 1024) ? 0.18033688f : 1.0f;   // 0.125 * log2(e)
            Wt[(size_t)n*DIM + kb*32 + tx] = f2b(tile[tx][ty] * s);
        }
    }
}

// ---------------- kernel 2: QKV GEMM, XCD-swizzled grid, LDS-restaged epilogue ----------------
// 1D grid, 768 blocks. xcd = id&7 (dispatch round-robin): XCD x owns n-tiles
// {3x,3x+1,3x+2} -> 768 KB of B resident in that XCD's 4 MB L2; consecutive
// slots share the same A-stripe (temporal locality).
#define LDC 136
__global__ __launch_bounds__(256) void qkv_gemm_kernel(
    const unsigned short* __restrict__ A,
    const unsigned short* __restrict__ Bt,
    unsigned short* __restrict__ Qw,
    unsigned short* __restrict__ Kw,
    unsigned short* __restrict__ Vtw)
{
    __shared__ __align__(16) unsigned char smem[128 * LDC * 2];   // 34816 B
    unsigned short* As = (unsigned short*)smem;
    unsigned short* Bs = (unsigned short*)(smem + 16384);
    unsigned short* Cs = (unsigned short*)smem;

    const int tid  = threadIdx.x;
    const int id   = blockIdx.x;
    const int xcd  = id & 7;
    const int slot = id >> 3;                 // 0..95
    const int m0   = (slot / 3) * 128;        // 0..31 m-tiles
    const int n0   = (xcd * 3 + slot % 3) * 128;  // 0..23 n-tiles
    const int w    = tid >> 6;
    const int lane = tid & 63;
    const int l16  = lane & 15;
    const int quad = lane >> 4;
    const int wm   = (w >> 1) * 64;
    const int wn   = (w & 1) * 64;
    const int srow = lane >> 3;
    const int scol = (lane & 7) * 8;

    f32x4 acc[4][4];
    const f32x4 fzero = {0.f, 0.f, 0.f, 0.f};
    for (int i = 0; i < 4; i++)
        for (int j = 0; j < 4; j++) acc[i][j] = fzero;

    const unsigned short* Ag = A  + (size_t)(m0 + w * 32 + srow) * DIM + scol;
    const unsigned short* Bg = Bt + (size_t)(n0 + w * 32 + srow) * DIM + scol;

    for (int kt = 0; kt < DIM; kt += 64) {
        #pragma unroll
        for (int j = 0; j < 4; j++) {
            __builtin_amdgcn_global_load_lds((gu32*)(Ag + kt + (size_t)j * 8 * DIM),
                                             (su32*)&As[(w * 32 + j * 8) * 64], 16, 0, 0);
            __builtin_amdgcn_global_load_lds((gu32*)(Bg + kt + (size_t)j * 8 * DIM),
                                             (su32*)&Bs[(w * 32 + j * 8) * 64], 16, 0, 0);
        }
        __syncthreads();
        #pragma unroll
        for (int s = 0; s < 2; s++) {
            bf16x8 af[4], bfr[4];
            #pragma unroll
            for (int i = 0; i < 4; i++) {
                af[i]  = *(const bf16x8*)(&As[(wm + i * 16 + l16) * 64 + s * 32 + quad * 8]);
                bfr[i] = *(const bf16x8*)(&Bs[(wn + i * 16 + l16) * 64 + s * 32 + quad * 8]);
            }
            #pragma unroll
            for (int i = 0; i < 4; i++)
                #pragma unroll
                for (int j = 0; j < 4; j++)
                    acc[i][j] = __builtin_amdgcn_mfma_f32_16x16x32_bf16(af[i], bfr[j], acc[i][j], 0, 0, 0);
        }
        __syncthreads();
    }

    const int part = n0 >> 10;
    const int h0   = (n0 & 1023) >> 6;
    const int b    = m0 >> 11;
    const int np0  = m0 & 2047;

    if (part < 2) {
        #pragma unroll
        for (int i = 0; i < 4; i++)
            #pragma unroll
            for (int j = 0; j < 4; j++)
                #pragma unroll
                for (int r = 0; r < 4; r++)
                    Cs[(wm + i * 16 + quad * 4 + r) * LDC + wn + j * 16 + l16] = f2b(acc[i][j][r]);
        __syncthreads();
        unsigned short* dst = (part == 0) ? Qw : Kw;
        #pragma unroll
        for (int pass = 0; pass < 8; pass++) {
            int mi = pass * 16 + (tid >> 4);
            int ci = (tid & 15) * 8;
            uint4 v = *(const uint4*)&Cs[mi * LDC + ci];
            int bh = b * HEADS + h0 + (ci >> 6);
            *(uint4*)&dst[((size_t)bh * SEQ + np0 + mi) * DHEAD + (ci & 63)] = v;
        }
    } else {
        #pragma unroll
        for (int i = 0; i < 4; i++)
            #pragma unroll
            for (int j = 0; j < 4; j++) {
                ushort4 pk;
                pk.x = f2b(acc[i][j][0]); pk.y = f2b(acc[i][j][1]);
                pk.z = f2b(acc[i][j][2]); pk.w = f2b(acc[i][j][3]);
                *(ushort4*)&Cs[(wn + j * 16 + l16) * LDC + wm + i * 16 + quad * 4] = pk;
            }
        __syncthreads();
        #pragma unroll
        for (int pass = 0; pass < 8; pass++) {
            int ci = pass * 16 + (tid >> 4);
            int mi = (tid & 15) * 8;
            uint4 v = *(const uint4*)&Cs[ci * LDC + mi];
            int bh = b * HEADS + h0 + (ci >> 6);
            *(uint4*)&Vtw[((size_t)bh * DHEAD + (ci & 63)) * SEQ + np0 + mi] = v;
        }
    }
}

// ---------------- kernel 3: flash attention + residual ----------------
// R7 addressing (no swizzle — R8 showed it increased conflicts), but with
// double-buffered LDS and ONE barrier per 64-key tile. Key-permuted S^T keeps
// P in-register; denominator on the MFMA pipe via ones-vector.
#define LDK 72
__global__ __launch_bounds__(256) void attn_kernel(
    const unsigned short* __restrict__ Qw,
    const unsigned short* __restrict__ Kw,
    const unsigned short* __restrict__ Vtw,
    const float* __restrict__ x,
    float* __restrict__ out)
{
    __shared__ __align__(16) unsigned short Ks[2][64 * LDK];  // [key][d]
    __shared__ __align__(16) unsigned short Vs[2][64 * LDK];  // V^T: [d][key]
    const int id  = blockIdx.x;
    const int qt  = id >> 5;
    const int bh  = ((id & 7) << 2) | ((id >> 3) & 3);        // 4 bh per XCD
    const int tid = threadIdx.x;
    const int w   = tid >> 6, lane = tid & 63;
    const int l16 = lane & 15, quad = lane >> 4;

    const unsigned short* Qbase = Qw + ((size_t)bh * SEQ + qt * 64 + w * 16 + l16) * DHEAD;
    bf16x8 qf[2];
    qf[0] = *(const bf16x8*)(Qbase + quad * 8);
    qf[1] = *(const bf16x8*)(Qbase + 32 + quad * 8);

    const int prow = ((l16 >> 2) << 3) | (l16 & 3);

    bf16x8 ones;
    #pragma unroll
    for (int j = 0; j < 8; j++) ones[j] = (bf16)1.0f;

    f32x4 o[4], dsum;
    const f32x4 fzero = {0.f, 0.f, 0.f, 0.f};
    #pragma unroll
    for (int d = 0; d < 4; d++) o[d] = fzero;
    dsum = fzero;

    const unsigned short* Kg = Kw  + (size_t)bh * SEQ * DHEAD;
    const unsigned short* Vg = Vtw + (size_t)bh * DHEAD * SEQ;

    const int r0 = tid >> 3, c0 = (tid & 7) * 8;

    // prologue: stage tile 0 into buf 0, preload tile 1 into regs
    uint4 kreg0 = *(const uint4*)(Kg + (size_t)r0 * DHEAD + c0);
    uint4 kreg1 = *(const uint4*)(Kg + (size_t)(r0 + 32) * DHEAD + c0);
    uint4 vreg0 = *(const uint4*)(Vg + (size_t)r0 * SEQ + c0);
    uint4 vreg1 = *(const uint4*)(Vg + (size_t)(r0 + 32) * SEQ + c0);
    *(uint4*)&Ks[0][r0 * LDK + c0]        = kreg0;
    *(uint4*)&Ks[0][(r0 + 32) * LDK + c0] = kreg1;
    *(uint4*)&Vs[0][r0 * LDK + c0]        = vreg0;
    *(uint4*)&Vs[0][(r0 + 32) * LDK + c0] = vreg1;
    kreg0 = *(const uint4*)(Kg + (size_t)(64 + r0) * DHEAD + c0);
    kreg1 = *(const uint4*)(Kg + (size_t)(64 + r0 + 32) * DHEAD + c0);
    vreg0 = *(const uint4*)(Vg + (size_t)r0 * SEQ + 64 + c0);
    vreg1 = *(const uint4*)(Vg + (size_t)(r0 + 32) * SEQ + 64 + c0);
    __syncthreads();

    for (int t = 0; t < SEQ / 64; t++) {
        const int cur = t & 1, nxt = cur ^ 1;
        // stage tile t+1 into the other buffer
        *(uint4*)&Ks[nxt][r0 * LDK + c0]        = kreg0;
        *(uint4*)&Ks[nxt][(r0 + 32) * LDK + c0] = kreg1;
        *(uint4*)&Vs[nxt][r0 * LDK + c0]        = vreg0;
        *(uint4*)&Vs[nxt][(r0 + 32) * LDK + c0] = vreg1;
        // prefetch tile t+2 (wrap; tail loads harmless, L2-hot)
        int kvn = ((t + 2) & (SEQ / 64 - 1)) * 64;
        kreg0 = *(const uint4*)(Kg + (size_t)(kvn + r0) * DHEAD + c0);
        kreg1 = *(const uint4*)(Kg + (size_t)(kvn + r0 + 32) * DHEAD + c0);
        vreg0 = *(const uint4*)(Vg + (size_t)r0 * SEQ + kvn + c0);
        vreg1 = *(const uint4*)(Vg + (size_t)(r0 + 32) * SEQ + kvn + c0);

        // S^T = K_perm · Q^T on buffer `cur`
        f32x4 sacc[4];
        #pragma unroll
        for (int ki = 0; ki < 4; ki++) sacc[ki] = fzero;
        #pragma unroll
        for (int s = 0; s < 2; s++)
            #pragma unroll
            for (int ki = 0; ki < 4; ki++) {
                bf16x8 kf = *(const bf16x8*)(
                    &Ks[cur][((ki >> 1) * 32 + prow + (ki & 1) * 4) * LDK + s * 32 + quad * 8]);
                sacc[ki] = __builtin_amdgcn_mfma_f32_16x16x32_bf16(kf, qf[s], sacc[ki], 0, 0, 0);
            }

        // p = exp2(s); C-regs are the PV A-frags; denominator via ones-MFMA
        bf16x8 pf[2];
        #pragma unroll
        for (int s = 0; s < 2; s++)
            #pragma unroll
            for (int half = 0; half < 2; half++) {
                int ki = 2 * s + half;
                #pragma unroll
                for (int r = 0; r < 4; r++)
                    pf[s][half * 4 + r] = (bf16)__builtin_amdgcn_exp2f(sacc[ki][r]);
            }

        #pragma unroll
        for (int s = 0; s < 2; s++) {
            dsum = __builtin_amdgcn_mfma_f32_16x16x32_bf16(pf[s], ones, dsum, 0, 0, 0);
            #pragma unroll
            for (int d = 0; d < 4; d++) {
                bf16x8 vf = *(const bf16x8*)(&Vs[cur][(d * 16 + l16) * LDK + s * 32 + quad * 8]);
                o[d] = __builtin_amdgcn_mfma_f32_16x16x32_bf16(pf[s], vf, o[d], 0, 0, 0);
            }
        }
        __syncthreads();   // single barrier: separates my reads of `cur` and
                           // writes of `nxt` from other waves' next-iter accesses
    }

    // dsum[r] = denominator of query quad*4+r (replicated across l16 lanes)
    float lr[4];
    #pragma unroll
    for (int r = 0; r < 4; r++) lr[r] = __builtin_amdgcn_rcpf(dsum[r]);

    const int b = bh >> 4, h = bh & 15;
    #pragma unroll
    for (int di = 0; di < 4; di++)
        #pragma unroll
        for (int r = 0; r < 4; r++) {
            int np  = qt * 64 + w * 16 + quad * 4 + r;
            int col = h * 64 + di * 16 + l16;
            size_t g = ((size_t)(b * SEQ + np)) * DIM + col;
            out[g] = o[di][r] * lr[r] + x[g];
        }
}

extern "C" void kernel_launch(void* const* d_in, const int* in_sizes, int n_in,
                              void* d_out, int out_size, void* d_ws, size_t ws_size,
                              hipStream_t stream) {
    const float* x  = (const float*)d_in[0];   // [2,2048,1024]
    const float* Wq = (const float*)d_in[1];   // [1024,3072]
    float* out = (float*)d_out;

    unsigned short* xb = (unsigned short*)d_ws;                  // [4096][1024]
    unsigned short* Wt = xb + (size_t)M_TOT * DIM;               // [3072][1024]
    unsigned short* Qw = Wt + (size_t)NQKV * DIM;                // [32][2048][64]
    unsigned short* Kw = Qw + (size_t)32 * SEQ * DHEAD;          // [32][2048][64]
    unsigned short* Vt = Kw + (size_t)32 * SEQ * DHEAD;          // [32][64][2048]

    prep_kernel<<<CAST_BLOCKS + (NQKV / 32) * (DIM / 32), 256, 0, stream>>>(x, xb, Wq, Wt);
    qkv_gemm_kernel<<<768, 256, 0, stream>>>(xb, Wt, Qw, Kw, Vt);
    attn_kernel<<<(SEQ / 64) * 32, 256, 0, stream>>>(Qw, Kw, Vt, x, out);
}